// Round 1
// baseline (1766.001 us; speedup 1.0000x reference)
//
#include <hip/hip_runtime.h>

// Regrid: y[n, b] = sum_{k: rows[k]==b} w[k] * x[n, flip(cols[k])]
// x: (140, 721*1440) f32, rows/cols: (260640,) i32, w: (260640,) f32
// out: (140, 181*360) f32

#define NXS 1440
#define NYS 721
#define N_A_CONST (721 * 1440)
#define N_B_CONST (181 * 360)

__global__ void zero_kernel(float* __restrict__ out, int n) {
    int i = blockIdx.x * blockDim.x + threadIdx.x;
    int stride = gridDim.x * blockDim.x;
    for (; i < n; i += stride) out[i] = 0.0f;
}

__global__ void scatter_kernel(const float* __restrict__ x,
                               const int* __restrict__ rows,
                               const int* __restrict__ cols,
                               const float* __restrict__ w,
                               float* __restrict__ out,
                               int nnz) {
    int k = blockIdx.x * blockDim.x + threadIdx.x;
    if (k >= nnz) return;
    int n = blockIdx.y;

    int c = cols[k];
    int iy = c / NXS;               // magic-multiply, cheap
    int ix = c - iy * NXS;
    int cf = (NYS - 1 - iy) * NXS + ix;   // latitude flip fused into gather index

    float v = w[k] * x[(size_t)n * N_A_CONST + cf];
    atomicAdd(out + (size_t)n * N_B_CONST + rows[k], v);
}

extern "C" void kernel_launch(void* const* d_in, const int* in_sizes, int n_in,
                              void* d_out, int out_size, void* d_ws, size_t ws_size,
                              hipStream_t stream) {
    const float* x    = (const float*)d_in[0];
    const int*   rows = (const int*)d_in[1];
    const int*   cols = (const int*)d_in[2];
    const float* w    = (const float*)d_in[3];
    float* out = (float*)d_out;

    int nnz    = in_sizes[1];
    int nfield = in_sizes[0] / N_A_CONST;   // 140

    // Must zero every call: harness poisons once and graph-replays without
    // re-poisoning; atomics would otherwise accumulate across replays.
    zero_kernel<<<2048, 256, 0, stream>>>(out, out_size);

    dim3 grid((nnz + 255) / 256, nfield);
    scatter_kernel<<<grid, 256, 0, stream>>>(x, rows, cols, w, out, nnz);
}

// Round 2
// 573.955 us; speedup vs baseline: 3.0769x; 3.0769x over previous
//
#include <hip/hip_runtime.h>

// Regrid as two-phase streaming SpMM.
// y[n, b] = sum_{k: rows[k]==b} w[k] * x[n, flip(cols[k])]
// x: (140, 721*1440) f32, rows/cols: (260640,) i32, w: f32, out: (140, 181*360) f32.
//
// Per call (deterministic work):
//   sort nnz by flipped col at 64B granularity (hist -> scan -> scatter),
//   build CSR-by-row (hist -> scan -> jlist),
//   then per 16-field chunk: G1 gather (coalesced x reads -> contiguous g),
//   G2 segment-sum (full-line g reads, one plain store per output). No atomics
//   in the hot phases; d_out fully overwritten so no zeroing needed.

#define NXS 1440
#define NYS 721
#define N_A_CONST (721 * 1440)
#define N_B_CONST (181 * 360)
#define NBUCK ((N_A_CONST + 15) / 16)   // 64,890 line-granularity buckets
#define CHUNK 16

// ---------- preprocessing ----------

__device__ __forceinline__ int flip_col(int c) {
    int iy = c / NXS;
    int ix = c - iy * NXS;
    return (NYS - 1 - iy) * NXS + ix;
}

__global__ void hist_kernel(const int* __restrict__ rows, const int* __restrict__ cols,
                            int* __restrict__ bcount, int* __restrict__ rcount, int nnz) {
    int k = blockIdx.x * blockDim.x + threadIdx.x;
    if (k >= nnz) return;
    int cf = flip_col(cols[k]);
    atomicAdd(&bcount[cf >> 4], 1);
    atomicAdd(&rcount[rows[k]], 1);
}

// single-block exclusive scan, out[0..n] (out[n] = total). n up to ~65K.
__global__ void scan_kernel(const int* __restrict__ in, int* __restrict__ out, int n) {
    __shared__ int lds[1024];
    __shared__ int carry_s;
    if (threadIdx.x == 0) carry_s = 0;
    __syncthreads();
    for (int base = 0; base < n; base += 1024) {
        int i = base + (int)threadIdx.x;
        int v = (i < n) ? in[i] : 0;
        lds[threadIdx.x] = v;
        __syncthreads();
        #pragma unroll
        for (int off = 1; off < 1024; off <<= 1) {
            int t = (threadIdx.x >= (unsigned)off) ? lds[threadIdx.x - off] : 0;
            __syncthreads();
            lds[threadIdx.x] += t;
            __syncthreads();
        }
        int incl = lds[threadIdx.x];
        int carry = carry_s;
        if (i < n) out[i] = carry + incl - v;   // exclusive
        __syncthreads();
        if (threadIdx.x == 0) carry_s = carry + lds[1023];
        __syncthreads();
    }
    if (threadIdx.x == 0) out[n] = carry_s;
}

__global__ void scatter_perm_kernel(const int* __restrict__ rows, const int* __restrict__ cols,
                                    const float* __restrict__ w,
                                    const int* __restrict__ boff, int* __restrict__ bcur,
                                    int* __restrict__ perm_cf, float* __restrict__ perm_w,
                                    int* __restrict__ perm_row, int nnz) {
    int k = blockIdx.x * blockDim.x + threadIdx.x;
    if (k >= nnz) return;
    int cf = flip_col(cols[k]);
    int bu = cf >> 4;
    int j = boff[bu] + atomicAdd(&bcur[bu], 1);
    perm_cf[j] = cf;
    perm_w[j] = w[k];
    perm_row[j] = rows[k];
}

__global__ void build_jlist_kernel(const int* __restrict__ perm_row, const int* __restrict__ roff,
                                   int* __restrict__ rcur, int* __restrict__ jlist, int nnz) {
    int j = blockIdx.x * blockDim.x + threadIdx.x;
    if (j >= nnz) return;
    int b = perm_row[j];
    int pos = roff[b] + atomicAdd(&rcur[b], 1);
    jlist[pos] = j;
}

// ---------- hot phases ----------

// G1: thread per sorted nnz j; gathers CHUNK fields, stores one full 64B g line.
__global__ void gather_kernel(const float* __restrict__ x, const int* __restrict__ perm_cf,
                              const float* __restrict__ perm_w, float* __restrict__ g,
                              int nnz, int n0, int C) {
    int j = blockIdx.x * blockDim.x + threadIdx.x;
    if (j >= nnz) return;
    int cf = perm_cf[j];
    float wj = perm_w[j];
    float v[CHUNK];
    #pragma unroll
    for (int c = 0; c < CHUNK; ++c)
        v[c] = (c < C) ? wj * x[(size_t)(n0 + c) * N_A_CONST + cf] : 0.0f;
    float4* gp = (float4*)(g + (size_t)j * CHUNK);
    #pragma unroll
    for (int i = 0; i < CHUNK / 4; ++i)
        gp[i] = make_float4(v[4 * i], v[4 * i + 1], v[4 * i + 2], v[4 * i + 3]);
}

// G2: thread per output row b; sums full g lines of its nnz, writes CHUNK fields.
__global__ void reduce_kernel(const float* __restrict__ g, const int* __restrict__ jlist,
                              const int* __restrict__ roff, float* __restrict__ out,
                              int n0, int C) {
    int b = blockIdx.x * blockDim.x + threadIdx.x;
    if (b >= N_B_CONST) return;
    float acc[CHUNK];
    #pragma unroll
    for (int i = 0; i < CHUNK; ++i) acc[i] = 0.0f;
    int p0 = roff[b], p1 = roff[b + 1];
    for (int pos = p0; pos < p1; ++pos) {
        int j = jlist[pos];
        const float4* gp = (const float4*)(g + (size_t)j * CHUNK);
        #pragma unroll
        for (int i = 0; i < CHUNK / 4; ++i) {
            float4 a = gp[i];
            acc[4 * i + 0] += a.x;
            acc[4 * i + 1] += a.y;
            acc[4 * i + 2] += a.z;
            acc[4 * i + 3] += a.w;
        }
    }
    #pragma unroll
    for (int c = 0; c < CHUNK; ++c)
        if (c < C) out[(size_t)(n0 + c) * N_B_CONST + b] = acc[c];
}

// ---------- fallback (round-1 scatter, used only if ws too small) ----------

__global__ void zero_kernel(float* __restrict__ out, int n) {
    int i = blockIdx.x * blockDim.x + threadIdx.x;
    int stride = gridDim.x * blockDim.x;
    for (; i < n; i += stride) out[i] = 0.0f;
}

__global__ void scatter_fallback_kernel(const float* __restrict__ x, const int* __restrict__ rows,
                                        const int* __restrict__ cols, const float* __restrict__ w,
                                        float* __restrict__ out, int nnz) {
    int k = blockIdx.x * blockDim.x + threadIdx.x;
    if (k >= nnz) return;
    int n = blockIdx.y;
    int cf = flip_col(cols[k]);
    float v = w[k] * x[(size_t)n * N_A_CONST + cf];
    atomicAdd(out + (size_t)n * N_B_CONST + rows[k], v);
}

extern "C" void kernel_launch(void* const* d_in, const int* in_sizes, int n_in,
                              void* d_out, int out_size, void* d_ws, size_t ws_size,
                              hipStream_t stream) {
    const float* x    = (const float*)d_in[0];
    const int*   rows = (const int*)d_in[1];
    const int*   cols = (const int*)d_in[2];
    const float* w    = (const float*)d_in[3];
    float* out = (float*)d_out;

    int nnz    = in_sizes[1];
    int nfield = in_sizes[0] / N_A_CONST;   // 140

    // ws layout (ints). Count arrays first so one memset clears them all.
    size_t o = 0;
    size_t bcount_o = o; o += NBUCK;
    size_t bcur_o   = o; o += NBUCK;
    size_t rcount_o = o; o += N_B_CONST;
    size_t rcur_o   = o; o += N_B_CONST;
    size_t zero_span = o;                      // everything before here gets memset(0)
    size_t boff_o   = o; o += NBUCK + 1;
    size_t roff_o   = o; o += N_B_CONST + 1;
    size_t pcf_o    = o; o += nnz;
    size_t pw_o     = o; o += nnz;
    size_t prow_o   = o; o += nnz;
    size_t jlist_o  = o; o += nnz;
    o = (o + 3) & ~(size_t)3;                  // 16B-align g
    size_t g_o      = o; o += (size_t)nnz * CHUNK;
    size_t need_bytes = o * sizeof(int);

    if (ws_size < need_bytes) {
        // fallback: round-1 scatter path
        zero_kernel<<<2048, 256, 0, stream>>>(out, out_size);
        dim3 grid((nnz + 255) / 256, nfield);
        scatter_fallback_kernel<<<grid, 256, 0, stream>>>(x, rows, cols, w, out, nnz);
        return;
    }

    int*   wsI     = (int*)d_ws;
    int*   bcount  = wsI + bcount_o;
    int*   bcur    = wsI + bcur_o;
    int*   rcount  = wsI + rcount_o;
    int*   rcur    = wsI + rcur_o;
    int*   boff    = wsI + boff_o;
    int*   roff    = wsI + roff_o;
    int*   perm_cf = wsI + pcf_o;
    float* perm_w  = (float*)(wsI + pw_o);
    int*   perm_row= wsI + prow_o;
    int*   jlist   = wsI + jlist_o;
    float* g       = (float*)(wsI + g_o);

    hipMemsetAsync(wsI, 0, zero_span * sizeof(int), stream);

    int nblk = (nnz + 255) / 256;
    hist_kernel<<<nblk, 256, 0, stream>>>(rows, cols, bcount, rcount, nnz);
    scan_kernel<<<1, 1024, 0, stream>>>(bcount, boff, NBUCK);
    scan_kernel<<<1, 1024, 0, stream>>>(rcount, roff, N_B_CONST);
    scatter_perm_kernel<<<nblk, 256, 0, stream>>>(rows, cols, w, boff, bcur,
                                                  perm_cf, perm_w, perm_row, nnz);
    build_jlist_kernel<<<nblk, 256, 0, stream>>>(perm_row, roff, rcur, jlist, nnz);

    int rblk = (N_B_CONST + 255) / 256;
    for (int n0 = 0; n0 < nfield; n0 += CHUNK) {
        int C = nfield - n0;
        if (C > CHUNK) C = CHUNK;
        gather_kernel<<<nblk, 256, 0, stream>>>(x, perm_cf, perm_w, g, nnz, n0, C);
        reduce_kernel<<<rblk, 256, 0, stream>>>(g, jlist, roff, out, n0, C);
    }
}

// Round 3
// 453.245 us; speedup vs baseline: 3.8964x; 1.2663x over previous
//
#include <hip/hip_runtime.h>

// Regrid as two-phase streaming SpMM.
// y[n, b] = sum_{k: rows[k]==b} w[k] * x[n, flip(cols[k])]
// x: (140, 721*1440) f32, rows/cols: (260640,) i32, w: f32, out: (140, 181*360) f32.
//
// Per call: sort nnz by flipped col at 64B-line granularity (hist -> fast
// 2-block scan -> scatter that also emits the row-CSR jlist), then per
// 16-field chunk: G1 gather (line-coalesced x reads -> contiguous g lines),
// G2 segment-sum (4 lanes per output row read one full g line). No atomics in
// hot phases; d_out fully overwritten so no zeroing needed.

#define NXS 1440
#define NYS 721
#define N_A_CONST (721 * 1440)
#define N_B_CONST (181 * 360)
#define NBUCK ((N_A_CONST + 15) / 16)   // 64,890 line-granularity buckets
#define CHUNK 16

__device__ __forceinline__ int flip_col(int c) {
    int iy = c / NXS;
    int ix = c - iy * NXS;
    return (NYS - 1 - iy) * NXS + ix;
}

// ---------- preprocessing ----------

__global__ void hist_kernel(const int* __restrict__ rows, const int* __restrict__ cols,
                            int* __restrict__ bcount, int* __restrict__ rcount, int nnz) {
    int k = blockIdx.x * blockDim.x + threadIdx.x;
    if (k >= nnz) return;
    int cf = flip_col(cols[k]);
    atomicAdd(&bcount[cf >> 4], 1);
    atomicAdd(&rcount[rows[k]], 1);
}

// One block per array: block 0 scans bcount->boff (NBUCK), block 1 rcount->roff
// (N_B). 1024 threads x 64 serial elems = 65536 coverage. Exclusive; out[n]=total.
__global__ void scan2_kernel(const int* __restrict__ bcount, int* __restrict__ boff,
                             const int* __restrict__ rcount, int* __restrict__ roff) {
    const int* in; int* out; int n;
    if (blockIdx.x == 0) { in = bcount; out = boff; n = NBUCK; }
    else                 { in = rcount; out = roff; n = N_B_CONST; }

    int t = threadIdx.x;
    int base = t * 64;
    int s = 0;
    for (int i = 0; i < 64; ++i) {
        int idx = base + i;
        s += (idx < n) ? in[idx] : 0;
    }
    // wave64 inclusive scan of per-thread sums
    int lane = t & 63;
    int wv = t >> 6;
    int incl = s;
    #pragma unroll
    for (int off = 1; off < 64; off <<= 1) {
        int u = __shfl_up(incl, off, 64);
        if (lane >= off) incl += u;
    }
    __shared__ int wsum[16];
    if (lane == 63) wsum[wv] = incl;
    __syncthreads();
    if (t < 16) {
        int v = wsum[t];
        #pragma unroll
        for (int off = 1; off < 16; off <<= 1) {
            int u = __shfl_up(v, off, 16);
            if (t >= off) v += u;
        }
        wsum[t] = v;   // inclusive wave totals
    }
    __syncthreads();
    int waveoff = (wv == 0) ? 0 : wsum[wv - 1];
    int run = waveoff + incl - s;   // global exclusive prefix of this chunk
    for (int i = 0; i < 64; ++i) {
        int idx = base + i;
        if (idx < n) { out[idx] = run; run += in[idx]; }
    }
    if (t == 1023) out[n] = run;    // n <= 65160 < 65472, so run == total here
}

// Scatter into col-line-sorted order AND emit row-CSR jlist in one pass.
__global__ void scatter_perm_kernel(const int* __restrict__ rows, const int* __restrict__ cols,
                                    const float* __restrict__ w,
                                    const int* __restrict__ boff, int* __restrict__ bcur,
                                    const int* __restrict__ roff, int* __restrict__ rcur,
                                    int2* __restrict__ perm_cfw, int* __restrict__ jlist,
                                    int nnz) {
    int k = blockIdx.x * blockDim.x + threadIdx.x;
    if (k >= nnz) return;
    int cf = flip_col(cols[k]);
    int bu = cf >> 4;
    int j = boff[bu] + atomicAdd(&bcur[bu], 1);
    perm_cfw[j] = make_int2(cf, __float_as_int(w[k]));
    int b = rows[k];
    int pos = roff[b] + atomicAdd(&rcur[b], 1);
    jlist[pos] = j;
}

// ---------- hot phases ----------

// G1: thread per sorted nnz j; gathers CHUNK fields (line-coalesced within the
// wave thanks to the sort), stores one full 64B g line.
__global__ void gather_kernel(const float* __restrict__ x, const int2* __restrict__ perm_cfw,
                              float* __restrict__ g, int nnz, int n0, int C) {
    int j = blockIdx.x * blockDim.x + threadIdx.x;
    if (j >= nnz) return;
    int2 cfw = perm_cfw[j];
    int cf = cfw.x;
    float wj = __int_as_float(cfw.y);
    float v[CHUNK];
    #pragma unroll
    for (int c = 0; c < CHUNK; ++c)
        v[c] = (c < C) ? wj * x[(size_t)(n0 + c) * N_A_CONST + cf] : 0.0f;
    float4* gp = (float4*)(g + (size_t)j * CHUNK);
    #pragma unroll
    for (int i = 0; i < CHUNK / 4; ++i)
        gp[i] = make_float4(v[4 * i], v[4 * i + 1], v[4 * i + 2], v[4 * i + 3]);
}

// G2: 4 lanes per output row b (lane quarter q covers fields q*4..q*4+3).
// The 4 readers of each 64B g line are adjacent lanes -> one transaction.
__global__ void reduce_kernel(const float* __restrict__ g, const int* __restrict__ jlist,
                              const int* __restrict__ roff, float* __restrict__ out,
                              int n0, int C) {
    int tid = blockIdx.x * blockDim.x + threadIdx.x;
    int b = tid >> 2;
    int q = tid & 3;
    if (b >= N_B_CONST) return;
    int p0 = roff[b], p1 = roff[b + 1];
    float4 acc = make_float4(0.f, 0.f, 0.f, 0.f);
    for (int pos = p0; pos < p1; ++pos) {
        int j = jlist[pos];
        float4 a = *(const float4*)(g + (size_t)j * CHUNK + 4 * q);
        acc.x += a.x; acc.y += a.y; acc.z += a.z; acc.w += a.w;
    }
    int f0 = 4 * q;
    if (f0 + 0 < C) out[(size_t)(n0 + f0 + 0) * N_B_CONST + b] = acc.x;
    if (f0 + 1 < C) out[(size_t)(n0 + f0 + 1) * N_B_CONST + b] = acc.y;
    if (f0 + 2 < C) out[(size_t)(n0 + f0 + 2) * N_B_CONST + b] = acc.z;
    if (f0 + 3 < C) out[(size_t)(n0 + f0 + 3) * N_B_CONST + b] = acc.w;
}

// ---------- fallback (round-1 scatter, used only if ws too small) ----------

__global__ void zero_kernel(float* __restrict__ out, int n) {
    int i = blockIdx.x * blockDim.x + threadIdx.x;
    int stride = gridDim.x * blockDim.x;
    for (; i < n; i += stride) out[i] = 0.0f;
}

__global__ void scatter_fallback_kernel(const float* __restrict__ x, const int* __restrict__ rows,
                                        const int* __restrict__ cols, const float* __restrict__ w,
                                        float* __restrict__ out, int nnz) {
    int k = blockIdx.x * blockDim.x + threadIdx.x;
    if (k >= nnz) return;
    int n = blockIdx.y;
    int cf = flip_col(cols[k]);
    float v = w[k] * x[(size_t)n * N_A_CONST + cf];
    atomicAdd(out + (size_t)n * N_B_CONST + rows[k], v);
}

extern "C" void kernel_launch(void* const* d_in, const int* in_sizes, int n_in,
                              void* d_out, int out_size, void* d_ws, size_t ws_size,
                              hipStream_t stream) {
    const float* x    = (const float*)d_in[0];
    const int*   rows = (const int*)d_in[1];
    const int*   cols = (const int*)d_in[2];
    const float* w    = (const float*)d_in[3];
    float* out = (float*)d_out;

    int nnz    = in_sizes[1];
    int nfield = in_sizes[0] / N_A_CONST;   // 140

    // ws layout (int units). Count arrays first: one memset clears them all.
    size_t o = 0;
    size_t bcount_o = o; o += NBUCK;
    size_t bcur_o   = o; o += NBUCK;
    size_t rcount_o = o; o += N_B_CONST;
    size_t rcur_o   = o; o += N_B_CONST;
    size_t zero_span = o;
    size_t boff_o   = o; o += NBUCK + 1;
    size_t roff_o   = o; o += N_B_CONST + 1;
    o = (o + 3) & ~(size_t)3;
    size_t pcfw_o   = o; o += 2 * (size_t)nnz;     // int2
    size_t jlist_o  = o; o += nnz;
    o = (o + 3) & ~(size_t)3;                      // 16B-align g
    size_t g_o      = o; o += (size_t)nnz * CHUNK;
    size_t need_bytes = o * sizeof(int);

    if (ws_size < need_bytes) {
        zero_kernel<<<2048, 256, 0, stream>>>(out, out_size);
        dim3 grid((nnz + 255) / 256, nfield);
        scatter_fallback_kernel<<<grid, 256, 0, stream>>>(x, rows, cols, w, out, nnz);
        return;
    }

    int*   wsI      = (int*)d_ws;
    int*   bcount   = wsI + bcount_o;
    int*   bcur     = wsI + bcur_o;
    int*   rcount   = wsI + rcount_o;
    int*   rcur     = wsI + rcur_o;
    int*   boff     = wsI + boff_o;
    int*   roff     = wsI + roff_o;
    int2*  perm_cfw = (int2*)(wsI + pcfw_o);
    int*   jlist    = wsI + jlist_o;
    float* g        = (float*)(wsI + g_o);

    hipMemsetAsync(wsI, 0, zero_span * sizeof(int), stream);

    int nblk = (nnz + 255) / 256;
    hist_kernel<<<nblk, 256, 0, stream>>>(rows, cols, bcount, rcount, nnz);
    scan2_kernel<<<2, 1024, 0, stream>>>(bcount, boff, rcount, roff);
    scatter_perm_kernel<<<nblk, 256, 0, stream>>>(rows, cols, w, boff, bcur, roff, rcur,
                                                  perm_cfw, jlist, nnz);

    int rblk = (4 * N_B_CONST + 255) / 256;
    for (int n0 = 0; n0 < nfield; n0 += CHUNK) {
        int C = nfield - n0;
        if (C > CHUNK) C = CHUNK;
        gather_kernel<<<nblk, 256, 0, stream>>>(x, perm_cfw, g, nnz, n0, C);
        reduce_kernel<<<rblk, 256, 0, stream>>>(g, jlist, roff, out, n0, C);
    }
}

// Round 4
// 392.207 us; speedup vs baseline: 4.5027x; 1.1556x over previous
//
#include <hip/hip_runtime.h>

// Regrid as two-phase streaming SpMM.
// y[n, b] = sum_{k: rows[k]==b} w[k] * x[n, flip(cols[k])]
// x: (140, 721*1440) f32, rows/cols: (260640,) i32, w: f32, out: (140, 181*360) f32.
//
// Per call: sort nnz by flipped col at 64B-line granularity (hist -> 2-block
// scan -> scatter that also emits the row-CSR jlist), then ONE gather dispatch
// (all 140 fields, grid.y = field-chunk) writing g (nnz x 140 f32, chunked
// 64B lines), and ONE reduce dispatch (4 lanes per output row per chunk).
// No atomics in hot phases; d_out fully overwritten so no zeroing needed.

#define NXS 1440
#define NYS 721
#define N_A_CONST (721 * 1440)
#define N_B_CONST (181 * 360)
#define NBUCK ((N_A_CONST + 15) / 16)   // 64,890 line-granularity buckets
#define CHUNK 16

__device__ __forceinline__ int flip_col(int c) {
    int iy = c / NXS;
    int ix = c - iy * NXS;
    return (NYS - 1 - iy) * NXS + ix;
}

// ---------- preprocessing ----------

__global__ void hist_kernel(const int* __restrict__ rows, const int* __restrict__ cols,
                            int* __restrict__ bcount, int* __restrict__ rcount, int nnz) {
    int k = blockIdx.x * blockDim.x + threadIdx.x;
    if (k >= nnz) return;
    int cf = flip_col(cols[k]);
    atomicAdd(&bcount[cf >> 4], 1);
    atomicAdd(&rcount[rows[k]], 1);
}

// block 0: bcount->boff (NBUCK); block 1: rcount->roff (N_B). 1024 thr x 64.
__global__ void scan2_kernel(const int* __restrict__ bcount, int* __restrict__ boff,
                             const int* __restrict__ rcount, int* __restrict__ roff) {
    const int* in; int* out; int n;
    if (blockIdx.x == 0) { in = bcount; out = boff; n = NBUCK; }
    else                 { in = rcount; out = roff; n = N_B_CONST; }

    int t = threadIdx.x;
    int base = t * 64;
    int s = 0;
    for (int i = 0; i < 64; ++i) {
        int idx = base + i;
        s += (idx < n) ? in[idx] : 0;
    }
    int lane = t & 63;
    int wv = t >> 6;
    int incl = s;
    #pragma unroll
    for (int off = 1; off < 64; off <<= 1) {
        int u = __shfl_up(incl, off, 64);
        if (lane >= off) incl += u;
    }
    __shared__ int wsum[16];
    if (lane == 63) wsum[wv] = incl;
    __syncthreads();
    if (t < 16) {
        int v = wsum[t];
        #pragma unroll
        for (int off = 1; off < 16; off <<= 1) {
            int u = __shfl_up(v, off, 16);
            if (t >= off) v += u;
        }
        wsum[t] = v;
    }
    __syncthreads();
    int waveoff = (wv == 0) ? 0 : wsum[wv - 1];
    int run = waveoff + incl - s;
    for (int i = 0; i < 64; ++i) {
        int idx = base + i;
        if (idx < n) { out[idx] = run; run += in[idx]; }
    }
    if (t == 1023) out[n] = run;
}

// Scatter into col-line-sorted order AND emit row-CSR jlist in one pass.
__global__ void scatter_perm_kernel(const int* __restrict__ rows, const int* __restrict__ cols,
                                    const float* __restrict__ w,
                                    const int* __restrict__ boff, int* __restrict__ bcur,
                                    const int* __restrict__ roff, int* __restrict__ rcur,
                                    int2* __restrict__ perm_cfw, int* __restrict__ jlist,
                                    int nnz) {
    int k = blockIdx.x * blockDim.x + threadIdx.x;
    if (k >= nnz) return;
    int cf = flip_col(cols[k]);
    int bu = cf >> 4;
    int j = boff[bu] + atomicAdd(&bcur[bu], 1);
    perm_cfw[j] = make_int2(cf, __float_as_int(w[k]));
    int b = rows[k];
    int pos = roff[b] + atomicAdd(&rcur[b], 1);
    jlist[pos] = j;
}

// ---------- hot phases (one dispatch each) ----------

// G1: thread (j, chunk); gathers CHUNK fields (line-coalesced via the sort),
// stores one full 64B g line at g[(chunk*nnz + j)*CHUNK].
__global__ void gather_all_kernel(const float* __restrict__ x, const int2* __restrict__ perm_cfw,
                                  float* __restrict__ g, int nnz, int nfield) {
    int j = blockIdx.x * blockDim.x + threadIdx.x;
    if (j >= nnz) return;
    int chunk = blockIdx.y;
    int n0 = chunk * CHUNK;
    int C = nfield - n0; if (C > CHUNK) C = CHUNK;

    int2 cfw = perm_cfw[j];
    int cf = cfw.x;
    float wj = __int_as_float(cfw.y);
    float v[CHUNK];
    #pragma unroll
    for (int c = 0; c < CHUNK; ++c)
        v[c] = (c < C) ? wj * x[(size_t)(n0 + c) * N_A_CONST + cf] : 0.0f;
    float4* gp = (float4*)(g + ((size_t)chunk * nnz + j) * CHUNK);
    #pragma unroll
    for (int i = 0; i < CHUNK / 4; ++i)
        gp[i] = make_float4(v[4 * i], v[4 * i + 1], v[4 * i + 2], v[4 * i + 3]);
}

// G2: (b, q, chunk): 4 lanes per output row per chunk; the 4 readers of each
// 64B g line are adjacent lanes -> one transaction.
__global__ void reduce_all_kernel(const float* __restrict__ g, const int* __restrict__ jlist,
                                  const int* __restrict__ roff, float* __restrict__ out,
                                  int nnz, int nfield) {
    int tid = blockIdx.x * blockDim.x + threadIdx.x;
    int b = tid >> 2;
    int q = tid & 3;
    if (b >= N_B_CONST) return;
    int chunk = blockIdx.y;
    int n0 = chunk * CHUNK;
    int C = nfield - n0; if (C > CHUNK) C = CHUNK;

    const float* gc = g + (size_t)chunk * nnz * CHUNK;
    int p0 = roff[b], p1 = roff[b + 1];
    float4 acc = make_float4(0.f, 0.f, 0.f, 0.f);
    for (int pos = p0; pos < p1; ++pos) {
        int j = jlist[pos];
        float4 a = *(const float4*)(gc + (size_t)j * CHUNK + 4 * q);
        acc.x += a.x; acc.y += a.y; acc.z += a.z; acc.w += a.w;
    }
    int f0 = 4 * q;
    if (f0 + 0 < C) out[(size_t)(n0 + f0 + 0) * N_B_CONST + b] = acc.x;
    if (f0 + 1 < C) out[(size_t)(n0 + f0 + 1) * N_B_CONST + b] = acc.y;
    if (f0 + 2 < C) out[(size_t)(n0 + f0 + 2) * N_B_CONST + b] = acc.z;
    if (f0 + 3 < C) out[(size_t)(n0 + f0 + 3) * N_B_CONST + b] = acc.w;
}

// ---------- fallbacks ----------

__global__ void zero_kernel(float* __restrict__ out, int n) {
    int i = blockIdx.x * blockDim.x + threadIdx.x;
    int stride = gridDim.x * blockDim.x;
    for (; i < n; i += stride) out[i] = 0.0f;
}

__global__ void scatter_fallback_kernel(const float* __restrict__ x, const int* __restrict__ rows,
                                        const int* __restrict__ cols, const float* __restrict__ w,
                                        float* __restrict__ out, int nnz) {
    int k = blockIdx.x * blockDim.x + threadIdx.x;
    if (k >= nnz) return;
    int n = blockIdx.y;
    int cf = flip_col(cols[k]);
    float v = w[k] * x[(size_t)n * N_A_CONST + cf];
    atomicAdd(out + (size_t)n * N_B_CONST + rows[k], v);
}

// g chunked per 16 fields: thread (j), loop chunks (used if ws can't hold full g)
__global__ void gather_kernel(const float* __restrict__ x, const int2* __restrict__ perm_cfw,
                              float* __restrict__ g, int nnz, int n0, int C) {
    int j = blockIdx.x * blockDim.x + threadIdx.x;
    if (j >= nnz) return;
    int2 cfw = perm_cfw[j];
    int cf = cfw.x;
    float wj = __int_as_float(cfw.y);
    float v[CHUNK];
    #pragma unroll
    for (int c = 0; c < CHUNK; ++c)
        v[c] = (c < C) ? wj * x[(size_t)(n0 + c) * N_A_CONST + cf] : 0.0f;
    float4* gp = (float4*)(g + (size_t)j * CHUNK);
    #pragma unroll
    for (int i = 0; i < CHUNK / 4; ++i)
        gp[i] = make_float4(v[4 * i], v[4 * i + 1], v[4 * i + 2], v[4 * i + 3]);
}

__global__ void reduce_kernel(const float* __restrict__ g, const int* __restrict__ jlist,
                              const int* __restrict__ roff, float* __restrict__ out,
                              int n0, int C) {
    int tid = blockIdx.x * blockDim.x + threadIdx.x;
    int b = tid >> 2;
    int q = tid & 3;
    if (b >= N_B_CONST) return;
    int p0 = roff[b], p1 = roff[b + 1];
    float4 acc = make_float4(0.f, 0.f, 0.f, 0.f);
    for (int pos = p0; pos < p1; ++pos) {
        int j = jlist[pos];
        float4 a = *(const float4*)(g + (size_t)j * CHUNK + 4 * q);
        acc.x += a.x; acc.y += a.y; acc.z += a.z; acc.w += a.w;
    }
    int f0 = 4 * q;
    if (f0 + 0 < C) out[(size_t)(n0 + f0 + 0) * N_B_CONST + b] = acc.x;
    if (f0 + 1 < C) out[(size_t)(n0 + f0 + 1) * N_B_CONST + b] = acc.y;
    if (f0 + 2 < C) out[(size_t)(n0 + f0 + 2) * N_B_CONST + b] = acc.z;
    if (f0 + 3 < C) out[(size_t)(n0 + f0 + 3) * N_B_CONST + b] = acc.w;
}

extern "C" void kernel_launch(void* const* d_in, const int* in_sizes, int n_in,
                              void* d_out, int out_size, void* d_ws, size_t ws_size,
                              hipStream_t stream) {
    const float* x    = (const float*)d_in[0];
    const int*   rows = (const int*)d_in[1];
    const int*   cols = (const int*)d_in[2];
    const float* w    = (const float*)d_in[3];
    float* out = (float*)d_out;

    int nnz    = in_sizes[1];
    int nfield = in_sizes[0] / N_A_CONST;   // 140
    int nchunk = (nfield + CHUNK - 1) / CHUNK;

    // ws layout (int units). Count arrays first: one memset clears them all.
    size_t o = 0;
    size_t bcount_o = o; o += NBUCK;
    size_t bcur_o   = o; o += NBUCK;
    size_t rcount_o = o; o += N_B_CONST;
    size_t rcur_o   = o; o += N_B_CONST;
    size_t zero_span = o;
    size_t boff_o   = o; o += NBUCK + 1;
    size_t roff_o   = o; o += N_B_CONST + 1;
    o = (o + 3) & ~(size_t)3;
    size_t pcfw_o   = o; o += 2 * (size_t)nnz;     // int2
    size_t jlist_o  = o; o += nnz;
    o = (o + 3) & ~(size_t)3;                      // 16B-align g
    size_t g_o      = o;
    size_t need_full    = (g_o + (size_t)nchunk * nnz * CHUNK) * sizeof(int);
    size_t need_chunked = (g_o + (size_t)nnz * CHUNK) * sizeof(int);

    if (ws_size < need_chunked) {
        zero_kernel<<<2048, 256, 0, stream>>>(out, out_size);
        dim3 grid((nnz + 255) / 256, nfield);
        scatter_fallback_kernel<<<grid, 256, 0, stream>>>(x, rows, cols, w, out, nnz);
        return;
    }

    int*   wsI      = (int*)d_ws;
    int*   bcount   = wsI + bcount_o;
    int*   bcur     = wsI + bcur_o;
    int*   rcount   = wsI + rcount_o;
    int*   rcur     = wsI + rcur_o;
    int*   boff     = wsI + boff_o;
    int*   roff     = wsI + roff_o;
    int2*  perm_cfw = (int2*)(wsI + pcfw_o);
    int*   jlist    = wsI + jlist_o;
    float* g        = (float*)(wsI + g_o);

    hipMemsetAsync(wsI, 0, zero_span * sizeof(int), stream);

    int nblk = (nnz + 255) / 256;
    hist_kernel<<<nblk, 256, 0, stream>>>(rows, cols, bcount, rcount, nnz);
    scan2_kernel<<<2, 1024, 0, stream>>>(bcount, boff, rcount, roff);
    scatter_perm_kernel<<<nblk, 256, 0, stream>>>(rows, cols, w, boff, bcur, roff, rcur,
                                                  perm_cfw, jlist, nnz);

    int rblk = (4 * N_B_CONST + 255) / 256;
    if (ws_size >= need_full) {
        // hot path: 2 dispatches total
        dim3 ggrid(nblk, nchunk), rgrid(rblk, nchunk);
        gather_all_kernel<<<ggrid, 256, 0, stream>>>(x, perm_cfw, g, nnz, nfield);
        reduce_all_kernel<<<rgrid, 256, 0, stream>>>(g, jlist, roff, out, nnz, nfield);
    } else {
        for (int n0 = 0; n0 < nfield; n0 += CHUNK) {
            int C = nfield - n0;
            if (C > CHUNK) C = CHUNK;
            gather_kernel<<<nblk, 256, 0, stream>>>(x, perm_cfw, g, nnz, n0, C);
            reduce_kernel<<<rblk, 256, 0, stream>>>(g, jlist, roff, out, n0, C);
        }
    }
}